// Round 12
// baseline (94.259 us; speedup 1.0000x reference)
//
#include <hip/hip_runtime.h>

#define NB 8
#define NC 4
#define HH 256
#define WW 256
#define HW_ (HH * WW)
#define NSL 24      // NB * (NC-1)
#define CT 4        // columns per env tile (also rows/thread in phase B)
#define NT (WW/CT)  // 64 column tiles
#define HP (HH + 1) // padded LDS stride
#define GRIDN (NSL * NT)

typedef unsigned long long u64;

// Block = one image row (n,h). Softmax+CE (fast-math), write p[1..3], emit
// row bit-masks (bit = column w) for fg (tgt==c) and pred (p_c>=0.5).
__global__ __launch_bounds__(256) void k_softmax_ce(
    const float* __restrict__ pred, const int* __restrict__ tgt,
    float* __restrict__ pbuf, u64* __restrict__ rmT, u64* __restrict__ rmP,
    double* __restrict__ pce) {
  int b = blockIdx.x;            // n*HH + h
  int n = b >> 8, h = b & (HH - 1);
  int w = threadIdx.x;
  size_t base = (size_t)n * NC * HW_ + (size_t)h * WW + w;
  float x0 = pred[base];
  float x1 = pred[base + HW_];
  float x2 = pred[base + 2 * HW_];
  float x3 = pred[base + 3 * HW_];
  float mx = fmaxf(fmaxf(x0, x1), fmaxf(x2, x3));
  float e0 = __expf(x0 - mx), e1 = __expf(x1 - mx);
  float e2 = __expf(x2 - mx), e3 = __expf(x3 - mx);
  float sum = e0 + e1 + e2 + e3;
  float lse = mx + __logf(sum);
  int t = tgt[(size_t)n * HW_ + h * WW + w];
  float xt = (t == 0) ? x0 : (t == 1) ? x1 : (t == 2) ? x2 : x3;
  float ce = lse - xt;
  float inv = 1.0f / sum;
  float p1 = e1 * inv, p2 = e2 * inv, p3 = e3 * inv;
  size_t pb = ((size_t)(n * 3)) * HW_ + (size_t)h * WW + w;
  pbuf[pb]           = p1;
  pbuf[pb + HW_]     = p2;
  pbuf[pb + 2 * HW_] = p3;
  u64 bT1 = __ballot(t == 1), bP1 = __ballot(p1 >= 0.5f);
  u64 bT2 = __ballot(t == 2), bP2 = __ballot(p2 >= 0.5f);
  u64 bT3 = __ballot(t == 3), bP3 = __ballot(p3 >= 0.5f);
  int v = threadIdx.x >> 6;
  if ((threadIdx.x & 63) == 0) {
    size_t mi = ((size_t)(n * 3) * HH + h) * 4 + v;   // slice s = n*3 + (c-1)
    rmT[mi]                      = bT1;  rmP[mi]                      = bP1;
    rmT[mi + (size_t)HH * 4]     = bT2;  rmP[mi + (size_t)HH * 4]     = bP2;
    rmT[mi + (size_t)2 * HH * 4] = bT3;  rmP[mi + (size_t)2 * HH * 4] = bP3;
  }
  double cd = (double)ce;
  #pragma unroll
  for (int o = 32; o > 0; o >>= 1) cd += __shfl_down(cd, o, 64);
  if ((threadIdx.x & 63) == 0) pce[(b << 2) | v] = cd;
}

// Nearest set bit at index <= bit (incl.) in 256-bit mask; 10000 if none.
template<int WORD>
__device__ __forceinline__ int nsb_left(u64 m0, u64 m1, u64 m2, u64 m3, int bit) {
  u64 cur = (WORD == 0) ? m0 : (WORD == 1) ? m1 : (WORD == 2) ? m2 : m3;
  u64 below = cur & ((bit == 63) ? ~0ull : ((1ull << (bit + 1)) - 1ull));
  if (below) return bit - (63 - (int)__builtin_clzll(below));
  if constexpr (WORD >= 1) {
    u64 x = (WORD == 1) ? m0 : (WORD == 2) ? m1 : m2;
    if (x) return bit + 1 + (int)__builtin_clzll(x);
  }
  if constexpr (WORD >= 2) {
    u64 x = (WORD == 2) ? m0 : m1;
    if (x) return bit + 65 + (int)__builtin_clzll(x);
  }
  if constexpr (WORD >= 3) {
    if (m0) return bit + 129 + (int)__builtin_clzll(m0);
  }
  return 10000;
}

// Nearest set bit at index >= bit (incl.); 10000 if none.
template<int WORD>
__device__ __forceinline__ int nsb_right(u64 m0, u64 m1, u64 m2, u64 m3, int bit) {
  u64 cur = (WORD == 0) ? m0 : (WORD == 1) ? m1 : (WORD == 2) ? m2 : m3;
  u64 above = cur & (~0ull << bit);
  if (above) return (int)__builtin_ctzll(above) - bit;
  if constexpr (WORD <= 2) {
    u64 x = (WORD == 0) ? m1 : (WORD == 1) ? m2 : m3;
    if (x) return 64 + (int)__builtin_ctzll(x) - bit;
  }
  if constexpr (WORD <= 1) {
    u64 x = (WORD == 0) ? m2 : m3;
    if (x) return 128 + (int)__builtin_ctzll(x) - bit;
  }
  if constexpr (WORD == 0) {
    if (m3) return 192 + (int)__builtin_ctzll(m3) - bit;
  }
  return 10000;
}

// Scan-based tile fill: seed left/right distances once at tile edges, then
// propagate d = seed ? 0 : min(d+1, 10000). Also returns this thread's g^2
// values in myF/myB/myQ registers for the column-min reduction.
template<int WORD>
__device__ __forceinline__ void filltile(
    u64 t0, u64 t1, u64 t2, u64 t3, u64 p0, u64 p1, u64 p2, u64 p3,
    int h, int bit0, float gF[CT][HP], float gB[CT][HP], float gQ[CT][HP],
    unsigned char gtb[CT][HH + 4],
    float myF[CT], float myB[CT], float myQ[CT]) {
  u64 b0 = ~t0, b1 = ~t1, b2 = ~t2, b3 = ~t3;
  u64 curT = (WORD == 0) ? t0 : (WORD == 1) ? t1 : (WORD == 2) ? t2 : t3;
  u64 curP = (WORD == 0) ? p0 : (WORD == 1) ? p1 : (WORD == 2) ? p2 : p3;
  int dF[CT], dB[CT], dQ[CT];
  int lF = nsb_left<WORD>(t0, t1, t2, t3, bit0);
  int lB = nsb_left<WORD>(b0, b1, b2, b3, bit0);
  int lP = nsb_left<WORD>(p0, p1, p2, p3, bit0);
  #pragma unroll
  for (int wi = 0; wi < CT; ++wi) {
    int bit = bit0 + wi;
    int sF = (int)((curT >> bit) & 1ull);
    int sP = (int)((curP >> bit) & 1ull);
    if (wi > 0) {
      lF = sF ? 0 : min(lF + 1, 10000);
      lB = sF ? min(lB + 1, 10000) : 0;   // bg seed = !sF
      lP = sP ? 0 : min(lP + 1, 10000);
    }
    dF[wi] = lF; dB[wi] = lB; dQ[wi] = lP;
  }
  int rF = nsb_right<WORD>(t0, t1, t2, t3, bit0 + CT - 1);
  int rB = nsb_right<WORD>(b0, b1, b2, b3, bit0 + CT - 1);
  int rP = nsb_right<WORD>(p0, p1, p2, p3, bit0 + CT - 1);
  #pragma unroll
  for (int wi = CT - 1; wi >= 0; --wi) {
    int bit = bit0 + wi;
    int sF = (int)((curT >> bit) & 1ull);
    int sP = (int)((curP >> bit) & 1ull);
    if (wi < CT - 1) {
      rF = sF ? 0 : min(rF + 1, 10000);
      rB = sF ? min(rB + 1, 10000) : 0;
      rP = sP ? 0 : min(rP + 1, 10000);
    }
    int vF = min(dF[wi], rF), vB = min(dB[wi], rB), vQ = min(dQ[wi], rP);
    float fF = (float)(vF * vF), fB = (float)(vB * vB), fQ = (float)(vQ * vQ);
    gF[wi][h] = fF;
    gB[wi][h] = fB;
    gQ[wi][h] = fQ;
    myF[wi] = fF; myB[wi] = fB; myQ[wi] = fQ;
    gtb[wi][h] = (unsigned char)sF;
  }
}

// Block = (slice s, 4-column tile). Phase A: thread = row h, row-DT from bit
// masks -> LDS + per-column g-min (shfl reduce). Phase B: outward envelope
// along H with EXACT column-min prune: stop when r^2 + colMin >= m (no y at
// distance >= r can improve; float-monotone => bit-identical result).
__global__ __launch_bounds__(256) void k_env(
    const u64* __restrict__ rmT, const u64* __restrict__ rmP,
    const float* __restrict__ pbuf, double* __restrict__ part) {
  __shared__ float gF[CT][HP];
  __shared__ float gB[CT][HP];
  __shared__ float gQ[CT][HP];
  __shared__ float pp[CT][HP];
  __shared__ unsigned char gtb[CT][HH + 4];
  __shared__ float cmin[4][CT * 3];   // per-wave column mins
  __shared__ double sbuf[12];
  int tid = threadIdx.x;
  int s  = blockIdx.x;
  int w0 = blockIdx.y * CT;
  int h  = tid;
  float myF[CT], myB[CT], myQ[CT];
  {
    size_t mi = ((size_t)s * HH + h) * 4;
    const ulonglong2* pT = (const ulonglong2*)(rmT + mi);
    const ulonglong2* pP = (const ulonglong2*)(rmP + mi);
    ulonglong2 a0 = pT[0], a1 = pT[1];
    ulonglong2 c0 = pP[0], c1 = pP[1];
    const float* prow = pbuf + (size_t)s * HW_ + (size_t)h * WW + w0;
    float4 pa = *(const float4*)prow;
    pp[0][h] = pa.x; pp[1][h] = pa.y; pp[2][h] = pa.z; pp[3][h] = pa.w;
    int bit0 = w0 & 63;
    switch (w0 >> 6) {
      case 0: filltile<0>(a0.x,a0.y,a1.x,a1.y,c0.x,c0.y,c1.x,c1.y,h,bit0,gF,gB,gQ,gtb,myF,myB,myQ); break;
      case 1: filltile<1>(a0.x,a0.y,a1.x,a1.y,c0.x,c0.y,c1.x,c1.y,h,bit0,gF,gB,gQ,gtb,myF,myB,myQ); break;
      case 2: filltile<2>(a0.x,a0.y,a1.x,a1.y,c0.x,c0.y,c1.x,c1.y,h,bit0,gF,gB,gQ,gtb,myF,myB,myQ); break;
      default: filltile<3>(a0.x,a0.y,a1.x,a1.y,c0.x,c0.y,c1.x,c1.y,h,bit0,gF,gB,gQ,gtb,myF,myB,myQ); break;
    }
  }
  // per-column min across the block: 64-lane shfl reduce, then 4-wave combine
  {
    #pragma unroll
    for (int wi = 0; wi < CT; ++wi) {
      #pragma unroll
      for (int o = 32; o > 0; o >>= 1) {
        myF[wi] = fminf(myF[wi], __shfl_xor(myF[wi], o, 64));
        myB[wi] = fminf(myB[wi], __shfl_xor(myB[wi], o, 64));
        myQ[wi] = fminf(myQ[wi], __shfl_xor(myQ[wi], o, 64));
      }
    }
    int lane = tid & 63, wv = tid >> 6;
    if (lane == 0) {
      #pragma unroll
      for (int wi = 0; wi < CT; ++wi) {
        cmin[wv][wi * 3]     = myF[wi];
        cmin[wv][wi * 3 + 1] = myB[wi];
        cmin[wv][wi * 3 + 2] = myQ[wi];
      }
    }
  }
  __syncthreads();
  int wi = tid & (CT - 1);
  int hg = tid >> 2;                // 0..63, each owns CT=4 rows
  float cmF = fminf(fminf(cmin[0][wi*3],   cmin[1][wi*3]),
                    fminf(cmin[2][wi*3],   cmin[3][wi*3]));
  float cmB = fminf(fminf(cmin[0][wi*3+1], cmin[1][wi*3+1]),
                    fminf(cmin[2][wi*3+1], cmin[3][wi*3+1]));
  float cmQ = fminf(fminf(cmin[0][wi*3+2], cmin[1][wi*3+2]),
                    fminf(cmin[2][wi*3+2], cmin[3][wi*3+2]));
  double a_bd = 0.0, a_t1 = 0.0, a_t2 = 0.0;
  for (int k = 0; k < CT; ++k) {
    int h2 = hg * CT + k;
    float mF = gF[wi][h2], mB = gB[wi][h2], mQ = gQ[wi][h2];
    // 4-batched exact outward search with column-min prune: candidates at
    // distance >= r all have fl(g+rr') >= fl(colMin+rr) >= m once the test
    // fires, so skipping them leaves the exact min unchanged.
    for (int r = 1; r < HH; r += 4) {
      float rr = (float)(r * r);
      if (rr + cmF >= mF && rr + cmB >= mB && rr + cmQ >= mQ) break;
      #pragma unroll
      for (int q = 0; q < 4; ++q) {
        int rq = r + q;
        float rrq = (float)(rq * rq);
        int u = h2 - rq, d = h2 + rq;
        if (u >= 0) {
          float fF = gF[wi][u], fB = gB[wi][u], fQ = gQ[wi][u];
          mF = fminf(mF, fF + rrq);
          mB = fminf(mB, fB + rrq);
          mQ = fminf(mQ, fQ + rrq);
        }
        if (d < HH) {
          float fF = gF[wi][d], fB = gB[wi][d], fQ = gQ[wi][d];
          mF = fminf(mF, fF + rrq);
          mB = fminf(mB, fB + rrq);
          mQ = fminf(mQ, fQ + rrq);
        }
      }
    }
    float dfg = sqrtf(mF), dbg = sqrtf(mB), dpr = sqrtf(mQ);
    float p  = pp[wi][h2];
    float gt = (float)gtb[wi][h2];
    a_bd += (double)(p * (dfg - dbg));
    a_t1 += (double)(p * dfg * dfg);
    a_t2 += (double)(gt * dpr * dpr);
  }
  int lane = tid & 63, wid = tid >> 6;
  #pragma unroll
  for (int o = 32; o > 0; o >>= 1) {
    a_bd += __shfl_down(a_bd, o, 64);
    a_t1 += __shfl_down(a_t1, o, 64);
    a_t2 += __shfl_down(a_t2, o, 64);
  }
  if (lane == 0) { sbuf[wid*3] = a_bd; sbuf[wid*3+1] = a_t1; sbuf[wid*3+2] = a_t2; }
  __syncthreads();
  if (tid == 0) {
    double b = 0, t1 = 0, t2 = 0;
    #pragma unroll
    for (int i = 0; i < 4; ++i) { b += sbuf[i*3]; t1 += sbuf[i*3+1]; t2 += sbuf[i*3+2]; }
    size_t pi = ((size_t)s * NT + blockIdx.y) * 4;
    part[pi] = b; part[pi+1] = t1; part[pi+2] = t2;
  }
}

__global__ __launch_bounds__(256) void k_final(const double* __restrict__ pce,
    const double* __restrict__ part, float* __restrict__ out) {
  __shared__ double sb[16];
  int t = threadIdx.x;
  double ce = 0.0, bd = 0.0, t1 = 0.0, t2 = 0.0;
  for (int i = t; i < NB * HH * 4; i += 256) ce += pce[i];
  for (int i = t; i < NSL * NT; i += 256) {
    bd += part[(size_t)i * 4];
    t1 += part[(size_t)i * 4 + 1];
    t2 += part[(size_t)i * 4 + 2];
  }
  int lane = t & 63, wid = t >> 6;
  #pragma unroll
  for (int o = 32; o > 0; o >>= 1) {
    ce += __shfl_down(ce, o, 64);
    bd += __shfl_down(bd, o, 64);
    t1 += __shfl_down(t1, o, 64);
    t2 += __shfl_down(t2, o, 64);
  }
  if (lane == 0) { sb[wid*4]=ce; sb[wid*4+1]=bd; sb[wid*4+2]=t1; sb[wid*4+3]=t2; }
  __syncthreads();
  if (t == 0) {
    double c = 0, b = 0, u1 = 0, u2 = 0;
    #pragma unroll
    for (int i = 0; i < 4; ++i) { c += sb[i*4]; b += sb[i*4+1]; u1 += sb[i*4+2]; u2 += sb[i*4+3]; }
    c /= (double)(NB * HW_);
    b /= (double)NSL;
    double hd = (u1 + u2) / ((double)HW_ * (double)(2 * NB * (NC - 1)));
    out[0] = (float)(c + 0.5 * b + 0.5 * hd);
    out[1] = (float)c;
    out[2] = (float)b;
    out[3] = (float)hd;
  }
}

extern "C" void kernel_launch(void* const* d_in, const int* in_sizes, int n_in,
                              void* d_out, int out_size, void* d_ws, size_t ws_size,
                              hipStream_t stream) {
  (void)in_sizes; (void)n_in; (void)out_size; (void)ws_size;
  const float* pred = (const float*)d_in[0];
  const int*   tgt  = (const int*)d_in[1];
  float* out = (float*)d_out;
  char* ws = (char*)d_ws;
  double* pce  = (double*)ws;                             // 8192 doubles (64KB)
  double* part = (double*)(ws + 65536);                   // 1536*4 doubles (48KB)
  float*  pbuf = (float*)(ws + 131072);                   // 24*HW floats (6.29MB)
  u64* rmT = (u64*)(ws + 131072 + (size_t)NSL * HW_ * 4); // 196KB
  u64* rmP = rmT + (size_t)NSL * HH * 4;                  // 196KB

  hipLaunchKernelGGL(k_softmax_ce, dim3(NB * HH), dim3(256), 0, stream,
                     pred, tgt, pbuf, rmT, rmP, pce);
  hipLaunchKernelGGL(k_env, dim3(NSL, NT), dim3(256), 0, stream,
                     rmT, rmP, pbuf, part);
  hipLaunchKernelGGL(k_final, dim3(1), dim3(256), 0, stream, pce, part, out);
}

// Round 15
// 83.853 us; speedup vs baseline: 1.1241x; 1.1241x over previous
//
#include <hip/hip_runtime.h>

#define NB 8
#define NC 4
#define HH 256
#define WW 256
#define HW_ (HH * WW)
#define NSL 24      // NB * (NC-1)
#define CT 8        // columns per env tile
#define NT (WW/CT)  // 32 column tiles
#define HP (HH + 1) // padded LDS stride
#define GRIDN (NSL * NT)

typedef unsigned long long u64;

// Block = one image row (n,h). Softmax+CE (fast-math), write p[1..3], emit
// row bit-masks (bit = column w) for fg (tgt==c) and pred (p_c>=0.5).
__global__ __launch_bounds__(256) void k_softmax_ce(
    const float* __restrict__ pred, const int* __restrict__ tgt,
    float* __restrict__ pbuf, u64* __restrict__ rmT, u64* __restrict__ rmP,
    double* __restrict__ pce) {
  int b = blockIdx.x;            // n*HH + h
  int n = b >> 8, h = b & (HH - 1);
  int w = threadIdx.x;
  size_t base = (size_t)n * NC * HW_ + (size_t)h * WW + w;
  float x0 = pred[base];
  float x1 = pred[base + HW_];
  float x2 = pred[base + 2 * HW_];
  float x3 = pred[base + 3 * HW_];
  float mx = fmaxf(fmaxf(x0, x1), fmaxf(x2, x3));
  float e0 = __expf(x0 - mx), e1 = __expf(x1 - mx);
  float e2 = __expf(x2 - mx), e3 = __expf(x3 - mx);
  float sum = e0 + e1 + e2 + e3;
  float lse = mx + __logf(sum);
  int t = tgt[(size_t)n * HW_ + h * WW + w];
  float xt = (t == 0) ? x0 : (t == 1) ? x1 : (t == 2) ? x2 : x3;
  float ce = lse - xt;
  float inv = 1.0f / sum;
  float p1 = e1 * inv, p2 = e2 * inv, p3 = e3 * inv;
  size_t pb = ((size_t)(n * 3)) * HW_ + (size_t)h * WW + w;
  pbuf[pb]           = p1;
  pbuf[pb + HW_]     = p2;
  pbuf[pb + 2 * HW_] = p3;
  u64 bT1 = __ballot(t == 1), bP1 = __ballot(p1 >= 0.5f);
  u64 bT2 = __ballot(t == 2), bP2 = __ballot(p2 >= 0.5f);
  u64 bT3 = __ballot(t == 3), bP3 = __ballot(p3 >= 0.5f);
  int v = threadIdx.x >> 6;
  if ((threadIdx.x & 63) == 0) {
    size_t mi = ((size_t)(n * 3) * HH + h) * 4 + v;   // slice s = n*3 + (c-1)
    rmT[mi]                      = bT1;  rmP[mi]                      = bP1;
    rmT[mi + (size_t)HH * 4]     = bT2;  rmP[mi + (size_t)HH * 4]     = bP2;
    rmT[mi + (size_t)2 * HH * 4] = bT3;  rmP[mi + (size_t)2 * HH * 4] = bP3;
  }
  double cd = (double)ce;
  #pragma unroll
  for (int o = 32; o > 0; o >>= 1) cd += __shfl_down(cd, o, 64);
  if ((threadIdx.x & 63) == 0) pce[(b << 2) | v] = cd;
}

// Nearest set bit at index <= bit (incl.) in 256-bit mask; 10000 if none.
template<int WORD>
__device__ __forceinline__ int nsb_left(u64 m0, u64 m1, u64 m2, u64 m3, int bit) {
  u64 cur = (WORD == 0) ? m0 : (WORD == 1) ? m1 : (WORD == 2) ? m2 : m3;
  u64 below = cur & ((bit == 63) ? ~0ull : ((1ull << (bit + 1)) - 1ull));
  if (below) return bit - (63 - (int)__builtin_clzll(below));
  if constexpr (WORD >= 1) {
    u64 x = (WORD == 1) ? m0 : (WORD == 2) ? m1 : m2;
    if (x) return bit + 1 + (int)__builtin_clzll(x);
  }
  if constexpr (WORD >= 2) {
    u64 x = (WORD == 2) ? m0 : m1;
    if (x) return bit + 65 + (int)__builtin_clzll(x);
  }
  if constexpr (WORD >= 3) {
    if (m0) return bit + 129 + (int)__builtin_clzll(m0);
  }
  return 10000;
}

// Nearest set bit at index >= bit (incl.); 10000 if none.
template<int WORD>
__device__ __forceinline__ int nsb_right(u64 m0, u64 m1, u64 m2, u64 m3, int bit) {
  u64 cur = (WORD == 0) ? m0 : (WORD == 1) ? m1 : (WORD == 2) ? m2 : m3;
  u64 above = cur & (~0ull << bit);
  if (above) return (int)__builtin_ctzll(above) - bit;
  if constexpr (WORD <= 2) {
    u64 x = (WORD == 0) ? m1 : (WORD == 1) ? m2 : m3;
    if (x) return 64 + (int)__builtin_ctzll(x) - bit;
  }
  if constexpr (WORD <= 1) {
    u64 x = (WORD == 0) ? m2 : m3;
    if (x) return 128 + (int)__builtin_ctzll(x) - bit;
  }
  if constexpr (WORD == 0) {
    if (m3) return 192 + (int)__builtin_ctzll(m3) - bit;
  }
  return 10000;
}

// Row-DT for fg (seeds = mask bits) and bg (seeds = complement) of one row,
// CT columns. Scan-based: seed edges once, propagate min(d+1, 10000).
template<int WORD>
__device__ __forceinline__ void filltileT(
    u64 t0, u64 t1, u64 t2, u64 t3, int h, int bit0,
    float gF[CT][HP], float gB[CT][HP], unsigned char gtb[CT][HH + 4]) {
  u64 b0 = ~t0, b1 = ~t1, b2 = ~t2, b3 = ~t3;
  u64 curT = (WORD == 0) ? t0 : (WORD == 1) ? t1 : (WORD == 2) ? t2 : t3;
  int dF[CT], dB[CT];
  int lF = nsb_left<WORD>(t0, t1, t2, t3, bit0);
  int lB = nsb_left<WORD>(b0, b1, b2, b3, bit0);
  #pragma unroll
  for (int wi = 0; wi < CT; ++wi) {
    int bit = bit0 + wi;
    int sF = (int)((curT >> bit) & 1ull);
    if (wi > 0) {
      lF = sF ? 0 : min(lF + 1, 10000);
      lB = sF ? min(lB + 1, 10000) : 0;
    }
    dF[wi] = lF; dB[wi] = lB;
  }
  int rF = nsb_right<WORD>(t0, t1, t2, t3, bit0 + CT - 1);
  int rB = nsb_right<WORD>(b0, b1, b2, b3, bit0 + CT - 1);
  #pragma unroll
  for (int wi = CT - 1; wi >= 0; --wi) {
    int bit = bit0 + wi;
    int sF = (int)((curT >> bit) & 1ull);
    if (wi < CT - 1) {
      rF = sF ? 0 : min(rF + 1, 10000);
      rB = sF ? min(rB + 1, 10000) : 0;
    }
    int vF = min(dF[wi], rF), vB = min(dB[wi], rB);
    gF[wi][h] = (float)(vF * vF);
    gB[wi][h] = (float)(vB * vB);
    gtb[wi][h] = (unsigned char)sF;
  }
}

// Row-DT for pred mask only.
template<int WORD>
__device__ __forceinline__ void filltileP(
    u64 p0, u64 p1, u64 p2, u64 p3, int h, int bit0, float gQ[CT][HP]) {
  u64 curP = (WORD == 0) ? p0 : (WORD == 1) ? p1 : (WORD == 2) ? p2 : p3;
  int dQ[CT];
  int lP = nsb_left<WORD>(p0, p1, p2, p3, bit0);
  #pragma unroll
  for (int wi = 0; wi < CT; ++wi) {
    int bit = bit0 + wi;
    int sP = (int)((curP >> bit) & 1ull);
    if (wi > 0) lP = sP ? 0 : min(lP + 1, 10000);
    dQ[wi] = lP;
  }
  int rP = nsb_right<WORD>(p0, p1, p2, p3, bit0 + CT - 1);
  #pragma unroll
  for (int wi = CT - 1; wi >= 0; --wi) {
    int bit = bit0 + wi;
    int sP = (int)((curP >> bit) & 1ull);
    if (wi < CT - 1) rP = sP ? 0 : min(rP + 1, 10000);
    int vQ = min(dQ[wi], rP);
    gQ[wi][h] = (float)(vQ * vQ);
  }
}

// Block = (slice s, 8-column tile), 512 threads (8 waves).
// Phase A (split): tid<256 -> F,B,gtb from rmT; tid>=256 -> Q from rmP + pp.
// Phase B: thread = (wi, hg) owns 4 consecutive rows, searched r-synchronized
// with shared 7-wide windows (4x fewer dependent LDS rounds than per-row).
__global__ __launch_bounds__(512) void k_env(
    const u64* __restrict__ rmT, const u64* __restrict__ rmP,
    const float* __restrict__ pbuf, double* __restrict__ part) {
  __shared__ float gF[CT][HP];
  __shared__ float gB[CT][HP];
  __shared__ float gQ[CT][HP];
  __shared__ float pp[CT][HP];
  __shared__ unsigned char gtb[CT][HH + 4];
  __shared__ double sbuf[24];
  int tid = threadIdx.x;
  int s  = blockIdx.x;
  int w0 = blockIdx.y * CT;
  int h  = tid & 255;
  int bit0 = w0 & 63;
  if (tid < 256) {
    size_t mi = ((size_t)s * HH + h) * 4;
    const ulonglong2* pT = (const ulonglong2*)(rmT + mi);
    ulonglong2 a0 = pT[0], a1 = pT[1];
    switch (w0 >> 6) {
      case 0: filltileT<0>(a0.x, a0.y, a1.x, a1.y, h, bit0, gF, gB, gtb); break;
      case 1: filltileT<1>(a0.x, a0.y, a1.x, a1.y, h, bit0, gF, gB, gtb); break;
      case 2: filltileT<2>(a0.x, a0.y, a1.x, a1.y, h, bit0, gF, gB, gtb); break;
      default: filltileT<3>(a0.x, a0.y, a1.x, a1.y, h, bit0, gF, gB, gtb); break;
    }
  } else {
    size_t mi = ((size_t)s * HH + h) * 4;
    const ulonglong2* pP = (const ulonglong2*)(rmP + mi);
    ulonglong2 c0 = pP[0], c1 = pP[1];
    switch (w0 >> 6) {
      case 0: filltileP<0>(c0.x, c0.y, c1.x, c1.y, h, bit0, gQ); break;
      case 1: filltileP<1>(c0.x, c0.y, c1.x, c1.y, h, bit0, gQ); break;
      case 2: filltileP<2>(c0.x, c0.y, c1.x, c1.y, h, bit0, gQ); break;
      default: filltileP<3>(c0.x, c0.y, c1.x, c1.y, h, bit0, gQ); break;
    }
    const float* prow = pbuf + (size_t)s * HW_ + (size_t)h * WW + w0;
    float4 pa = *(const float4*)prow;
    float4 pc = *(const float4*)(prow + 4);
    pp[0][h] = pa.x; pp[1][h] = pa.y; pp[2][h] = pa.z; pp[3][h] = pa.w;
    pp[4][h] = pc.x; pp[5][h] = pc.y; pp[6][h] = pc.z; pp[7][h] = pc.w;
  }
  __syncthreads();
  int wi = tid & (CT - 1);
  int hg = tid >> 3;                // 0..63, owns rows h0..h0+3
  int h0 = hg * 4;
  float mF[4], mB[4], mQ[4];
  #pragma unroll
  for (int k = 0; k < 4; ++k) {
    mF[k] = gF[wi][h0 + k];
    mB[k] = gB[wi][h0 + k];
    mQ[k] = gQ[wi][h0 + k];
  }
  // r-synchronized joint search over the 4 rows. Window up = g[h0-r-3..h0+3-r]
  // (7 vals), down = g[h0+r..h0+r+6]; candidate (k,q): up idx k-q+3, down k+q.
  // Same f32 adds/mins as per-row search over a candidate superset => exact.
  for (int r = 1; r < HH; r += 4) {
    float rr = (float)(r * r);
    bool need = false;
    #pragma unroll
    for (int k = 0; k < 4; ++k)
      need = need || (rr < mF[k]) || (rr < mB[k]) || (rr < mQ[k]);
    if (!need) break;
    float uF[7], uB[7], uQ[7], dFv[7], dBv[7], dQv[7];
    #pragma unroll
    for (int j = 0; j < 7; ++j) {
      int iu = h0 - r - 3 + j;
      int id = h0 + r + j;
      bool vu = (iu >= 0), vd = (id < HH);
      int cu = vu ? iu : 0, cd = vd ? id : (HH - 1);
      uF[j]  = vu ? gF[wi][cu] : 1e30f;
      uB[j]  = vu ? gB[wi][cu] : 1e30f;
      uQ[j]  = vu ? gQ[wi][cu] : 1e30f;
      dFv[j] = vd ? gF[wi][cd] : 1e30f;
      dBv[j] = vd ? gB[wi][cd] : 1e30f;
      dQv[j] = vd ? gQ[wi][cd] : 1e30f;
    }
    #pragma unroll
    for (int k = 0; k < 4; ++k) {
      #pragma unroll
      for (int q = 0; q < 4; ++q) {
        int rq = r + q;
        float rrq = (float)(rq * rq);
        mF[k] = fminf(mF[k], uF[k - q + 3] + rrq);
        mB[k] = fminf(mB[k], uB[k - q + 3] + rrq);
        mQ[k] = fminf(mQ[k], uQ[k - q + 3] + rrq);
        mF[k] = fminf(mF[k], dFv[k + q] + rrq);
        mB[k] = fminf(mB[k], dBv[k + q] + rrq);
        mQ[k] = fminf(mQ[k], dQv[k + q] + rrq);
      }
    }
  }
  double a_bd = 0.0, a_t1 = 0.0, a_t2 = 0.0;
  #pragma unroll
  for (int k = 0; k < 4; ++k) {
    int h2 = h0 + k;
    float dfg = sqrtf(mF[k]), dbg = sqrtf(mB[k]), dpr = sqrtf(mQ[k]);
    float p  = pp[wi][h2];
    float gt = (float)gtb[wi][h2];
    a_bd += (double)(p * (dfg - dbg));
    a_t1 += (double)(p * dfg * dfg);
    a_t2 += (double)(gt * dpr * dpr);
  }
  int lane = tid & 63, wid = tid >> 6;   // 8 waves
  #pragma unroll
  for (int o = 32; o > 0; o >>= 1) {
    a_bd += __shfl_down(a_bd, o, 64);
    a_t1 += __shfl_down(a_t1, o, 64);
    a_t2 += __shfl_down(a_t2, o, 64);
  }
  if (lane == 0) { sbuf[wid*3] = a_bd; sbuf[wid*3+1] = a_t1; sbuf[wid*3+2] = a_t2; }
  __syncthreads();
  if (tid == 0) {
    double b = 0, t1 = 0, t2 = 0;
    #pragma unroll
    for (int i = 0; i < 8; ++i) { b += sbuf[i*3]; t1 += sbuf[i*3+1]; t2 += sbuf[i*3+2]; }
    size_t pi = ((size_t)s * NT + blockIdx.y) * 4;
    part[pi] = b; part[pi+1] = t1; part[pi+2] = t2;
  }
}

__global__ __launch_bounds__(256) void k_final(const double* __restrict__ pce,
    const double* __restrict__ part, float* __restrict__ out) {
  __shared__ double sb[16];
  int t = threadIdx.x;
  double ce = 0.0, bd = 0.0, t1 = 0.0, t2 = 0.0;
  for (int i = t; i < NB * HH * 4; i += 256) ce += pce[i];
  for (int i = t; i < NSL * NT; i += 256) {
    bd += part[(size_t)i * 4];
    t1 += part[(size_t)i * 4 + 1];
    t2 += part[(size_t)i * 4 + 2];
  }
  int lane = t & 63, wid = t >> 6;
  #pragma unroll
  for (int o = 32; o > 0; o >>= 1) {
    ce += __shfl_down(ce, o, 64);
    bd += __shfl_down(bd, o, 64);
    t1 += __shfl_down(t1, o, 64);
    t2 += __shfl_down(t2, o, 64);
  }
  if (lane == 0) { sb[wid*4]=ce; sb[wid*4+1]=bd; sb[wid*4+2]=t1; sb[wid*4+3]=t2; }
  __syncthreads();
  if (t == 0) {
    double c = 0, b = 0, u1 = 0, u2 = 0;
    #pragma unroll
    for (int i = 0; i < 4; ++i) { c += sb[i*4]; b += sb[i*4+1]; u1 += sb[i*4+2]; u2 += sb[i*4+3]; }
    c /= (double)(NB * HW_);
    b /= (double)NSL;
    double hd = (u1 + u2) / ((double)HW_ * (double)(2 * NB * (NC - 1)));
    out[0] = (float)(c + 0.5 * b + 0.5 * hd);
    out[1] = (float)c;
    out[2] = (float)b;
    out[3] = (float)hd;
  }
}

extern "C" void kernel_launch(void* const* d_in, const int* in_sizes, int n_in,
                              void* d_out, int out_size, void* d_ws, size_t ws_size,
                              hipStream_t stream) {
  (void)in_sizes; (void)n_in; (void)out_size; (void)ws_size;
  const float* pred = (const float*)d_in[0];
  const int*   tgt  = (const int*)d_in[1];
  float* out = (float*)d_out;
  char* ws = (char*)d_ws;
  double* pce  = (double*)ws;                             // 8192 doubles (64KB)
  double* part = (double*)(ws + 65536);                   // 768*4 doubles (24KB)
  float*  pbuf = (float*)(ws + 131072);                   // 24*HW floats (6.29MB)
  u64* rmT = (u64*)(ws + 131072 + (size_t)NSL * HW_ * 4); // 196KB
  u64* rmP = rmT + (size_t)NSL * HH * 4;                  // 196KB

  hipLaunchKernelGGL(k_softmax_ce, dim3(NB * HH), dim3(256), 0, stream,
                     pred, tgt, pbuf, rmT, rmP, pce);
  hipLaunchKernelGGL(k_env, dim3(NSL, NT), dim3(512), 0, stream,
                     rmT, rmP, pbuf, part);
  hipLaunchKernelGGL(k_final, dim3(1), dim3(256), 0, stream, pce, part, out);
}

// Round 16
// 77.881 us; speedup vs baseline: 1.2103x; 1.0767x over previous
//
#include <hip/hip_runtime.h>

#define NB 8
#define NC 4
#define HH 256
#define WW 256
#define HW_ (HH * WW)
#define NSL 24      // NB * (NC-1)
#define CT 8        // columns per env tile
#define NT (WW/CT)  // 32 column tiles
#define HP (HH + 1) // padded LDS stride
#define GRIDN (NSL * NT)

typedef unsigned long long u64;

// Block = 4 image rows; wave v = row b*4+v; lane l handles px w = 64k+l,
// k=0..3. Softmax+CE (fast-math), write p[1..3]; the 4 ballots per mask are
// directly the 4 row-mask words (bit l = column 64k+l). Per-wave CE partial.
__global__ __launch_bounds__(256) void k_softmax_ce(
    const float* __restrict__ pred, const int* __restrict__ tgt,
    float* __restrict__ pbuf, u64* __restrict__ rmT, u64* __restrict__ rmP,
    double* __restrict__ pce) {
  int v = threadIdx.x >> 6, l = threadIdx.x & 63;
  int row = blockIdx.x * 4 + v;    // n*HH + h
  int n = row >> 8, h = row & (HH - 1);
  size_t predbase = (size_t)n * NC * HW_ + (size_t)h * WW + l;
  size_t tgtbase  = (size_t)n * HW_ + (size_t)h * WW + l;
  size_t pbbase   = (size_t)(n * 3) * HW_ + (size_t)h * WW + l;
  double ced = 0.0;
  u64 bT1[4], bT2[4], bT3[4], bP1[4], bP2[4], bP3[4];
  #pragma unroll
  for (int k = 0; k < 4; ++k) {
    int off = k * 64;
    float x0 = pred[predbase + off];
    float x1 = pred[predbase + HW_ + off];
    float x2 = pred[predbase + 2 * HW_ + off];
    float x3 = pred[predbase + 3 * HW_ + off];
    float mx = fmaxf(fmaxf(x0, x1), fmaxf(x2, x3));
    float e0 = __expf(x0 - mx), e1 = __expf(x1 - mx);
    float e2 = __expf(x2 - mx), e3 = __expf(x3 - mx);
    float sum = e0 + e1 + e2 + e3;
    float lse = mx + __logf(sum);
    int t = tgt[tgtbase + off];
    float xt = (t == 0) ? x0 : (t == 1) ? x1 : (t == 2) ? x2 : x3;
    ced += (double)(lse - xt);
    float inv = 1.0f / sum;
    float p1 = e1 * inv, p2 = e2 * inv, p3 = e3 * inv;
    pbuf[pbbase + off]           = p1;
    pbuf[pbbase + HW_ + off]     = p2;
    pbuf[pbbase + 2 * HW_ + off] = p3;
    bT1[k] = __ballot(t == 1); bP1[k] = __ballot(p1 >= 0.5f);
    bT2[k] = __ballot(t == 2); bP2[k] = __ballot(p2 >= 0.5f);
    bT3[k] = __ballot(t == 3); bP3[k] = __ballot(p3 >= 0.5f);
  }
  if (l == 0) {
    size_t mi1 = ((size_t)(n * 3) * HH + h) * 4;
    size_t mi2 = mi1 + (size_t)HH * 4;
    size_t mi3 = mi1 + (size_t)2 * HH * 4;
    #pragma unroll
    for (int k = 0; k < 4; ++k) {
      rmT[mi1 + k] = bT1[k];  rmP[mi1 + k] = bP1[k];
      rmT[mi2 + k] = bT2[k];  rmP[mi2 + k] = bP2[k];
      rmT[mi3 + k] = bT3[k];  rmP[mi3 + k] = bP3[k];
    }
  }
  #pragma unroll
  for (int o = 32; o > 0; o >>= 1) ced += __shfl_down(ced, o, 64);
  if (l == 0) pce[row] = ced;
}

// Nearest set bit at index <= bit (incl.) in 256-bit mask; 10000 if none.
template<int WORD>
__device__ __forceinline__ int nsb_left(u64 m0, u64 m1, u64 m2, u64 m3, int bit) {
  u64 cur = (WORD == 0) ? m0 : (WORD == 1) ? m1 : (WORD == 2) ? m2 : m3;
  u64 below = cur & ((bit == 63) ? ~0ull : ((1ull << (bit + 1)) - 1ull));
  if (below) return bit - (63 - (int)__builtin_clzll(below));
  if constexpr (WORD >= 1) {
    u64 x = (WORD == 1) ? m0 : (WORD == 2) ? m1 : m2;
    if (x) return bit + 1 + (int)__builtin_clzll(x);
  }
  if constexpr (WORD >= 2) {
    u64 x = (WORD == 2) ? m0 : m1;
    if (x) return bit + 65 + (int)__builtin_clzll(x);
  }
  if constexpr (WORD >= 3) {
    if (m0) return bit + 129 + (int)__builtin_clzll(m0);
  }
  return 10000;
}

// Nearest set bit at index >= bit (incl.); 10000 if none.
template<int WORD>
__device__ __forceinline__ int nsb_right(u64 m0, u64 m1, u64 m2, u64 m3, int bit) {
  u64 cur = (WORD == 0) ? m0 : (WORD == 1) ? m1 : (WORD == 2) ? m2 : m3;
  u64 above = cur & (~0ull << bit);
  if (above) return (int)__builtin_ctzll(above) - bit;
  if constexpr (WORD <= 2) {
    u64 x = (WORD == 0) ? m1 : (WORD == 1) ? m2 : m3;
    if (x) return 64 + (int)__builtin_ctzll(x) - bit;
  }
  if constexpr (WORD <= 1) {
    u64 x = (WORD == 0) ? m2 : m3;
    if (x) return 128 + (int)__builtin_ctzll(x) - bit;
  }
  if constexpr (WORD == 0) {
    if (m3) return 192 + (int)__builtin_ctzll(m3) - bit;
  }
  return 10000;
}

// Row-DT for fg (seeds = mask bits) and bg (seeds = complement) of one row,
// CT columns. Scan-based: seed edges once, propagate min(d+1, 10000).
template<int WORD>
__device__ __forceinline__ void filltileT(
    u64 t0, u64 t1, u64 t2, u64 t3, int h, int bit0,
    float gF[CT][HP], float gB[CT][HP], unsigned char gtb[CT][HH + 4]) {
  u64 b0 = ~t0, b1 = ~t1, b2 = ~t2, b3 = ~t3;
  u64 curT = (WORD == 0) ? t0 : (WORD == 1) ? t1 : (WORD == 2) ? t2 : t3;
  int dF[CT], dB[CT];
  int lF = nsb_left<WORD>(t0, t1, t2, t3, bit0);
  int lB = nsb_left<WORD>(b0, b1, b2, b3, bit0);
  #pragma unroll
  for (int wi = 0; wi < CT; ++wi) {
    int bit = bit0 + wi;
    int sF = (int)((curT >> bit) & 1ull);
    if (wi > 0) {
      lF = sF ? 0 : min(lF + 1, 10000);
      lB = sF ? min(lB + 1, 10000) : 0;
    }
    dF[wi] = lF; dB[wi] = lB;
  }
  int rF = nsb_right<WORD>(t0, t1, t2, t3, bit0 + CT - 1);
  int rB = nsb_right<WORD>(b0, b1, b2, b3, bit0 + CT - 1);
  #pragma unroll
  for (int wi = CT - 1; wi >= 0; --wi) {
    int bit = bit0 + wi;
    int sF = (int)((curT >> bit) & 1ull);
    if (wi < CT - 1) {
      rF = sF ? 0 : min(rF + 1, 10000);
      rB = sF ? min(rB + 1, 10000) : 0;
    }
    int vF = min(dF[wi], rF), vB = min(dB[wi], rB);
    gF[wi][h] = (float)(vF * vF);
    gB[wi][h] = (float)(vB * vB);
    gtb[wi][h] = (unsigned char)sF;
  }
}

// Row-DT for pred mask only.
template<int WORD>
__device__ __forceinline__ void filltileP(
    u64 p0, u64 p1, u64 p2, u64 p3, int h, int bit0, float gQ[CT][HP]) {
  u64 curP = (WORD == 0) ? p0 : (WORD == 1) ? p1 : (WORD == 2) ? p2 : p3;
  int dQ[CT];
  int lP = nsb_left<WORD>(p0, p1, p2, p3, bit0);
  #pragma unroll
  for (int wi = 0; wi < CT; ++wi) {
    int bit = bit0 + wi;
    int sP = (int)((curP >> bit) & 1ull);
    if (wi > 0) lP = sP ? 0 : min(lP + 1, 10000);
    dQ[wi] = lP;
  }
  int rP = nsb_right<WORD>(p0, p1, p2, p3, bit0 + CT - 1);
  #pragma unroll
  for (int wi = CT - 1; wi >= 0; --wi) {
    int bit = bit0 + wi;
    int sP = (int)((curP >> bit) & 1ull);
    if (wi < CT - 1) rP = sP ? 0 : min(rP + 1, 10000);
    int vQ = min(dQ[wi], rP);
    gQ[wi][h] = (float)(vQ * vQ);
  }
}

// Block = (slice s, 8-column tile), 512 threads (8 waves).
// Phase A (split): tid<256 -> F,B,gtb from rmT; tid>=256 -> Q from rmP + pp.
// Phase B: thread = (wi, hg) owns 4 consecutive rows, searched r-synchronized
// with shared 7-wide windows (4x fewer dependent LDS rounds than per-row).
__global__ __launch_bounds__(512) void k_env(
    const u64* __restrict__ rmT, const u64* __restrict__ rmP,
    const float* __restrict__ pbuf, double* __restrict__ part) {
  __shared__ float gF[CT][HP];
  __shared__ float gB[CT][HP];
  __shared__ float gQ[CT][HP];
  __shared__ float pp[CT][HP];
  __shared__ unsigned char gtb[CT][HH + 4];
  __shared__ double sbuf[24];
  int tid = threadIdx.x;
  int s  = blockIdx.x;
  int w0 = blockIdx.y * CT;
  int h  = tid & 255;
  int bit0 = w0 & 63;
  if (tid < 256) {
    size_t mi = ((size_t)s * HH + h) * 4;
    const ulonglong2* pT = (const ulonglong2*)(rmT + mi);
    ulonglong2 a0 = pT[0], a1 = pT[1];
    switch (w0 >> 6) {
      case 0: filltileT<0>(a0.x, a0.y, a1.x, a1.y, h, bit0, gF, gB, gtb); break;
      case 1: filltileT<1>(a0.x, a0.y, a1.x, a1.y, h, bit0, gF, gB, gtb); break;
      case 2: filltileT<2>(a0.x, a0.y, a1.x, a1.y, h, bit0, gF, gB, gtb); break;
      default: filltileT<3>(a0.x, a0.y, a1.x, a1.y, h, bit0, gF, gB, gtb); break;
    }
  } else {
    size_t mi = ((size_t)s * HH + h) * 4;
    const ulonglong2* pP = (const ulonglong2*)(rmP + mi);
    ulonglong2 c0 = pP[0], c1 = pP[1];
    switch (w0 >> 6) {
      case 0: filltileP<0>(c0.x, c0.y, c1.x, c1.y, h, bit0, gQ); break;
      case 1: filltileP<1>(c0.x, c0.y, c1.x, c1.y, h, bit0, gQ); break;
      case 2: filltileP<2>(c0.x, c0.y, c1.x, c1.y, h, bit0, gQ); break;
      default: filltileP<3>(c0.x, c0.y, c1.x, c1.y, h, bit0, gQ); break;
    }
    const float* prow = pbuf + (size_t)s * HW_ + (size_t)h * WW + w0;
    float4 pa = *(const float4*)prow;
    float4 pc = *(const float4*)(prow + 4);
    pp[0][h] = pa.x; pp[1][h] = pa.y; pp[2][h] = pa.z; pp[3][h] = pa.w;
    pp[4][h] = pc.x; pp[5][h] = pc.y; pp[6][h] = pc.z; pp[7][h] = pc.w;
  }
  __syncthreads();
  int wi = tid & (CT - 1);
  int hg = tid >> 3;                // 0..63, owns rows h0..h0+3
  int h0 = hg * 4;
  float mF[4], mB[4], mQ[4];
  #pragma unroll
  for (int k = 0; k < 4; ++k) {
    mF[k] = gF[wi][h0 + k];
    mB[k] = gB[wi][h0 + k];
    mQ[k] = gQ[wi][h0 + k];
  }
  // r-synchronized joint search over the 4 rows. Window up = g[h0-r-3..h0+3-r]
  // (7 vals), down = g[h0+r..h0+r+6]; candidate (k,q): up idx k-q+3, down k+q.
  // Same f32 adds/mins as per-row search over a candidate superset => exact.
  for (int r = 1; r < HH; r += 4) {
    float rr = (float)(r * r);
    bool need = false;
    #pragma unroll
    for (int k = 0; k < 4; ++k)
      need = need || (rr < mF[k]) || (rr < mB[k]) || (rr < mQ[k]);
    if (!need) break;
    float uF[7], uB[7], uQ[7], dFv[7], dBv[7], dQv[7];
    #pragma unroll
    for (int j = 0; j < 7; ++j) {
      int iu = h0 - r - 3 + j;
      int id = h0 + r + j;
      bool vu = (iu >= 0), vd = (id < HH);
      int cu = vu ? iu : 0, cd = vd ? id : (HH - 1);
      uF[j]  = vu ? gF[wi][cu] : 1e30f;
      uB[j]  = vu ? gB[wi][cu] : 1e30f;
      uQ[j]  = vu ? gQ[wi][cu] : 1e30f;
      dFv[j] = vd ? gF[wi][cd] : 1e30f;
      dBv[j] = vd ? gB[wi][cd] : 1e30f;
      dQv[j] = vd ? gQ[wi][cd] : 1e30f;
    }
    #pragma unroll
    for (int k = 0; k < 4; ++k) {
      #pragma unroll
      for (int q = 0; q < 4; ++q) {
        int rq = r + q;
        float rrq = (float)(rq * rq);
        mF[k] = fminf(mF[k], uF[k - q + 3] + rrq);
        mB[k] = fminf(mB[k], uB[k - q + 3] + rrq);
        mQ[k] = fminf(mQ[k], uQ[k - q + 3] + rrq);
        mF[k] = fminf(mF[k], dFv[k + q] + rrq);
        mB[k] = fminf(mB[k], dBv[k + q] + rrq);
        mQ[k] = fminf(mQ[k], dQv[k + q] + rrq);
      }
    }
  }
  double a_bd = 0.0, a_t1 = 0.0, a_t2 = 0.0;
  #pragma unroll
  for (int k = 0; k < 4; ++k) {
    int h2 = h0 + k;
    float dfg = sqrtf(mF[k]), dbg = sqrtf(mB[k]), dpr = sqrtf(mQ[k]);
    float p  = pp[wi][h2];
    float gt = (float)gtb[wi][h2];
    a_bd += (double)(p * (dfg - dbg));
    a_t1 += (double)(p * dfg * dfg);
    a_t2 += (double)(gt * dpr * dpr);
  }
  int lane = tid & 63, wid = tid >> 6;   // 8 waves
  #pragma unroll
  for (int o = 32; o > 0; o >>= 1) {
    a_bd += __shfl_down(a_bd, o, 64);
    a_t1 += __shfl_down(a_t1, o, 64);
    a_t2 += __shfl_down(a_t2, o, 64);
  }
  if (lane == 0) { sbuf[wid*3] = a_bd; sbuf[wid*3+1] = a_t1; sbuf[wid*3+2] = a_t2; }
  __syncthreads();
  if (tid == 0) {
    double b = 0, t1 = 0, t2 = 0;
    #pragma unroll
    for (int i = 0; i < 8; ++i) { b += sbuf[i*3]; t1 += sbuf[i*3+1]; t2 += sbuf[i*3+2]; }
    size_t pi = ((size_t)s * NT + blockIdx.y) * 4;
    part[pi] = b; part[pi+1] = t1; part[pi+2] = t2;
  }
}

__global__ __launch_bounds__(256) void k_final(const double* __restrict__ pce,
    const double* __restrict__ part, float* __restrict__ out) {
  __shared__ double sb[16];
  int t = threadIdx.x;
  double ce = 0.0, bd = 0.0, t1 = 0.0, t2 = 0.0;
  for (int i = t; i < NB * HH; i += 256) ce += pce[i];
  for (int i = t; i < NSL * NT; i += 256) {
    bd += part[(size_t)i * 4];
    t1 += part[(size_t)i * 4 + 1];
    t2 += part[(size_t)i * 4 + 2];
  }
  int lane = t & 63, wid = t >> 6;
  #pragma unroll
  for (int o = 32; o > 0; o >>= 1) {
    ce += __shfl_down(ce, o, 64);
    bd += __shfl_down(bd, o, 64);
    t1 += __shfl_down(t1, o, 64);
    t2 += __shfl_down(t2, o, 64);
  }
  if (lane == 0) { sb[wid*4]=ce; sb[wid*4+1]=bd; sb[wid*4+2]=t1; sb[wid*4+3]=t2; }
  __syncthreads();
  if (t == 0) {
    double c = 0, b = 0, u1 = 0, u2 = 0;
    #pragma unroll
    for (int i = 0; i < 4; ++i) { c += sb[i*4]; b += sb[i*4+1]; u1 += sb[i*4+2]; u2 += sb[i*4+3]; }
    c /= (double)(NB * HW_);
    b /= (double)NSL;
    double hd = (u1 + u2) / ((double)HW_ * (double)(2 * NB * (NC - 1)));
    out[0] = (float)(c + 0.5 * b + 0.5 * hd);
    out[1] = (float)c;
    out[2] = (float)b;
    out[3] = (float)hd;
  }
}

extern "C" void kernel_launch(void* const* d_in, const int* in_sizes, int n_in,
                              void* d_out, int out_size, void* d_ws, size_t ws_size,
                              hipStream_t stream) {
  (void)in_sizes; (void)n_in; (void)out_size; (void)ws_size;
  const float* pred = (const float*)d_in[0];
  const int*   tgt  = (const int*)d_in[1];
  float* out = (float*)d_out;
  char* ws = (char*)d_ws;
  double* pce  = (double*)ws;                             // 2048 doubles (16KB)
  double* part = (double*)(ws + 65536);                   // 768*4 doubles (24KB)
  float*  pbuf = (float*)(ws + 131072);                   // 24*HW floats (6.29MB)
  u64* rmT = (u64*)(ws + 131072 + (size_t)NSL * HW_ * 4); // 196KB
  u64* rmP = rmT + (size_t)NSL * HH * 4;                  // 196KB

  hipLaunchKernelGGL(k_softmax_ce, dim3(NB * HH / 4), dim3(256), 0, stream,
                     pred, tgt, pbuf, rmT, rmP, pce);
  hipLaunchKernelGGL(k_env, dim3(NSL, NT), dim3(512), 0, stream,
                     rmT, rmP, pbuf, part);
  hipLaunchKernelGGL(k_final, dim3(1), dim3(256), 0, stream, pce, part, out);
}